// Round 1
// baseline (1751.770 us; speedup 1.0000x reference)
//
#include <hip/hip_runtime.h>
#include <hip/hip_bf16.h>

namespace {

constexpr int MD   = 2048;   // model dim
constexpr int SL   = 2048;   // sequence length
constexpr int QKVD = 3072;   // fused qkv dim
constexpr int KOFF = 2048;   // k column offset in fused
constexpr int VOFF = 2560;   // v column offset in fused
constexpr int KT   = 32;     // key tile for attention

// ---------------------------------------------------------------------------
// C[M][N] = A[M][K] @ B[N][K]^T + bias[N]     (fp32, single-buffered LDS)
// 128x128 tile, BK=16, 256 threads, 8x8 per-thread micro-tile (interleaved:
// rows ty*4+u (+64), cols tx*4+w (+64)) so LDS reads are float4.
// ---------------------------------------------------------------------------
template<int BK>
__global__ __launch_bounds__(256) void gemm_bt(const float* __restrict__ A,
                                               const float* __restrict__ B,
                                               const float* __restrict__ bias,
                                               float* __restrict__ C,
                                               int M, int N, int K) {
  constexpr int BM = 128, BN = 128;
  __shared__ float As[BK][BM + 4];   // +4 pad keeps 16B alignment, kills conflicts
  __shared__ float Bs[BK][BN + 4];

  const int tid = threadIdx.x;
  const int ty = tid >> 4;          // 0..15
  const int tx = tid & 15;          // 0..15
  const int bm = blockIdx.y * BM;
  const int bn = blockIdx.x * BN;
  const int lr = tid >> 2;          // 0..63  (tile row for global load)
  const int lk = (tid & 3) << 2;    // 0,4,8,12 (k offset for global load)

  float acc[8][8];
  #pragma unroll
  for (int i = 0; i < 8; ++i)
    #pragma unroll
    for (int j = 0; j < 8; ++j) acc[i][j] = 0.f;

  const float* Ap = A + (size_t)(bm + lr) * K + lk;
  const float* Bp = B + (size_t)(bn + lr) * K + lk;

  for (int k0 = 0; k0 < K; k0 += BK) {
    const float4 a0 = *(const float4*)(Ap + k0);
    const float4 a1 = *(const float4*)(Ap + k0 + (size_t)64 * K);
    const float4 b0 = *(const float4*)(Bp + k0);
    const float4 b1 = *(const float4*)(Bp + k0 + (size_t)64 * K);
    __syncthreads();   // previous iteration's compute done with LDS
    As[lk+0][lr] = a0.x; As[lk+1][lr] = a0.y; As[lk+2][lr] = a0.z; As[lk+3][lr] = a0.w;
    As[lk+0][lr+64] = a1.x; As[lk+1][lr+64] = a1.y; As[lk+2][lr+64] = a1.z; As[lk+3][lr+64] = a1.w;
    Bs[lk+0][lr] = b0.x; Bs[lk+1][lr] = b0.y; Bs[lk+2][lr] = b0.z; Bs[lk+3][lr] = b0.w;
    Bs[lk+0][lr+64] = b1.x; Bs[lk+1][lr+64] = b1.y; Bs[lk+2][lr+64] = b1.z; Bs[lk+3][lr+64] = b1.w;
    __syncthreads();

    #pragma unroll
    for (int kk = 0; kk < BK; ++kk) {
      const float4 A0 = *(const float4*)&As[kk][ty * 4];
      const float4 A1 = *(const float4*)&As[kk][ty * 4 + 64];
      const float4 B0 = *(const float4*)&Bs[kk][tx * 4];
      const float4 B1 = *(const float4*)&Bs[kk][tx * 4 + 64];
      const float av[8] = {A0.x, A0.y, A0.z, A0.w, A1.x, A1.y, A1.z, A1.w};
      const float bv[8] = {B0.x, B0.y, B0.z, B0.w, B1.x, B1.y, B1.z, B1.w};
      #pragma unroll
      for (int i = 0; i < 8; ++i)
        #pragma unroll
        for (int j = 0; j < 8; ++j)
          acc[i][j] += av[i] * bv[j];
    }
  }

  #pragma unroll
  for (int i = 0; i < 8; ++i) {
    const int row = bm + ty * 4 + (i & 3) + (i >> 2) * 64;
    #pragma unroll
    for (int jh = 0; jh < 2; ++jh) {
      const int col = bn + tx * 4 + jh * 64;
      const float4 bv = *(const float4*)&bias[col];
      float4 o;
      o.x = acc[i][jh * 4 + 0] + bv.x;
      o.y = acc[i][jh * 4 + 1] + bv.y;
      o.z = acc[i][jh * 4 + 2] + bv.z;
      o.w = acc[i][jh * 4 + 3] + bv.w;
      *(float4*)&C[(size_t)row * N + col] = o;
    }
  }
}

// ---------------------------------------------------------------------------
// GQA attention, fp32, flash-style online softmax.
// Layout: q[s][g*256+r*64+d], k[s][2048+g*64+d], v[s][2560+g*64+d] in fused.
// One q-row per LANE PAIR: lane 2i owns dims 0..31, lane 2i+1 owns 32..63
// (keeps q/O/s in ~130 VGPRs -> 3 waves/SIMD; 512 blocks x 4 waves = 2048
// waves = 2/SIMD resident). K/V tiles (KT=32 rows x 64) staged in LDS, read
// as wave-broadcast float4 (conflict-free). Scores held in registers with
// fully unrolled loops (no runtime reg indexing -> no scratch).
// ---------------------------------------------------------------------------
__global__ __launch_bounds__(256) void attn_kernel(const float* __restrict__ fused,
                                                   float* __restrict__ out) {
  const int t    = threadIdx.x;
  const int blk  = blockIdx.x;     // 0..511
  const int h    = blk >> 4;       // head 0..31
  const int rb   = blk & 15;       // row block 0..15 (128 rows each)
  const int g    = h >> 2;         // group 0..7
  const int r    = h & 3;          // rep in group
  const int rowl = t >> 1;         // 0..127
  const int half = t & 1;          // which 32 dims of d
  const int srow = rb * 128 + rowl;
  const int d0   = half * 32;
  const int kcol = KOFF + g * 64;
  const int vcol = VOFF + g * 64;

  __shared__ float Ks[KT][64];
  __shared__ float Vs[KT][64];

  float q[32], O[32], s[KT];
  const float* qp = &fused[(size_t)srow * QKVD + g * 256 + r * 64 + d0];
  #pragma unroll
  for (int e4 = 0; e4 < 8; ++e4) {
    const float4 v = *(const float4*)(qp + e4 * 4);
    q[e4*4+0] = v.x * 0.125f; q[e4*4+1] = v.y * 0.125f;
    q[e4*4+2] = v.z * 0.125f; q[e4*4+3] = v.w * 0.125f;
  }
  #pragma unroll
  for (int e = 0; e < 32; ++e) O[e] = 0.f;
  float m = -1e30f, l = 0.f;

  // cooperative K/V tile load indices: 256 threads, KT*64=2048 floats each
  const int lj = t >> 4;          // 0..15 (row, second row at +16)
  const int ld = (t & 15) * 4;    // 0..60

  #pragma unroll 1
  for (int kt = 0; kt < SL; kt += KT) {
    __syncthreads();   // previous tile's compute done
    *(float4*)&Ks[lj][ld]      = *(const float4*)&fused[(size_t)(kt + lj) * QKVD + kcol + ld];
    *(float4*)&Ks[lj + 16][ld] = *(const float4*)&fused[(size_t)(kt + lj + 16) * QKVD + kcol + ld];
    *(float4*)&Vs[lj][ld]      = *(const float4*)&fused[(size_t)(kt + lj) * QKVD + vcol + ld];
    *(float4*)&Vs[lj + 16][ld] = *(const float4*)&fused[(size_t)(kt + lj + 16) * QKVD + vcol + ld];
    __syncthreads();

    // ---- scores for this tile (each lane: partial dot over its 32 dims) ----
    float tmax = -1e30f;
    #pragma unroll
    for (int j = 0; j < KT; ++j) {
      const float4* kr = (const float4*)&Ks[j][d0];
      float p0 = 0.f, p1 = 0.f, p2 = 0.f, p3 = 0.f;
      #pragma unroll
      for (int e8 = 0; e8 < 8; ++e8) {
        const float4 kv = kr[e8];
        p0 += q[e8*4+0] * kv.x;
        p1 += q[e8*4+1] * kv.y;
        p2 += q[e8*4+2] * kv.z;
        p3 += q[e8*4+3] * kv.w;
      }
      const float part = (p0 + p1) + (p2 + p3);
      const float sj = part + __shfl_xor(part, 1, 64);   // combine the two halves
      s[j] = sj;
      tmax = fmaxf(tmax, sj);
    }

    // ---- online softmax update ----
    const float mnew = fmaxf(m, tmax);
    const float corr = __expf(m - mnew);
    l *= corr;
    #pragma unroll
    for (int e = 0; e < 32; ++e) O[e] *= corr;

    #pragma unroll
    for (int j = 0; j < KT; ++j) {
      const float p = __expf(s[j] - mnew);
      l += p;
      const float4* vr = (const float4*)&Vs[j][d0];
      #pragma unroll
      for (int e8 = 0; e8 < 8; ++e8) {
        const float4 vv = vr[e8];
        O[e8*4+0] += p * vv.x;
        O[e8*4+1] += p * vv.y;
        O[e8*4+2] += p * vv.z;
        O[e8*4+3] += p * vv.w;
      }
    }
    m = mnew;
  }

  const float inv = 1.f / l;
  float* op = &out[(size_t)srow * MD + g * 256 + r * 64 + d0];
  #pragma unroll
  for (int e4 = 0; e4 < 8; ++e4) {
    float4 v;
    v.x = O[e4*4+0] * inv; v.y = O[e4*4+1] * inv;
    v.z = O[e4*4+2] * inv; v.w = O[e4*4+3] * inv;
    *(float4*)(op + e4 * 4) = v;
  }
}

}  // namespace

extern "C" void kernel_launch(void* const* d_in, const int* in_sizes, int n_in,
                              void* d_out, int out_size, void* d_ws, size_t ws_size,
                              hipStream_t stream) {
  const float* x     = (const float*)d_in[0];
  const float* w_qkv = (const float*)d_in[1];
  const float* b_qkv = (const float*)d_in[2];
  const float* w_out = (const float*)d_in[3];
  const float* b_out = (const float*)d_in[4];
  float* out = (float*)d_out;

  float* fused   = (float*)d_ws;                  // [2048][3072] fp32, 24 MB
  float* attnout = fused + (size_t)SL * QKVD;     // [2048][2048] fp32, 16 MB

  // fused = x @ w_qkv^T + b_qkv
  gemm_bt<16><<<dim3(QKVD / 128, SL / 128), 256, 0, stream>>>(
      x, w_qkv, b_qkv, fused, SL, QKVD, MD);

  // attnout = GQA(fused)
  attn_kernel<<<dim3(512), 256, 0, stream>>>(fused, attnout);

  // out = attnout @ w_out^T + b_out
  gemm_bt<16><<<dim3(MD / 128, SL / 128), 256, 0, stream>>>(
      attnout, w_out, b_out, out, SL, MD, MD);
}

// Round 2
// 1382.160 us; speedup vs baseline: 1.2674x; 1.2674x over previous
//
#include <hip/hip_runtime.h>
#include <hip/hip_bf16.h>

namespace {

constexpr int MD   = 2048;   // model dim
constexpr int SL   = 2048;   // sequence length
constexpr int QKVD = 3072;   // fused qkv dim
constexpr int KOFF = 2048;   // k column offset in fused
constexpr int VOFF = 2560;   // v column offset in fused
constexpr int KT   = 32;     // key tile for attention

typedef short  short8 __attribute__((ext_vector_type(8)));   // 8 bf16 = 4 VGPRs (MFMA operand)
typedef float  f32x4  __attribute__((ext_vector_type(4)));   // MFMA accumulator

struct alignas(8) us4 { unsigned short x, y, z, w; };

__device__ __forceinline__ unsigned short f2bf(float x) {   // fp32 -> bf16 RNE
  unsigned int u = __float_as_uint(x);
  u += 0x7FFFu + ((u >> 16) & 1u);
  return (unsigned short)(u >> 16);
}
__device__ __forceinline__ float bf2f(unsigned short h) {
  return __uint_as_float(((unsigned int)h) << 16);
}

// ---------------------------------------------------------------------------
// fp32 -> (bf16 hi, bf16 lo) split, 4 elems/thread. hi+lo ~ 16 mantissa bits.
// ---------------------------------------------------------------------------
__global__ __launch_bounds__(256) void split_kernel(const float* __restrict__ in,
                                                    unsigned short* __restrict__ hi,
                                                    unsigned short* __restrict__ lo,
                                                    int n4) {
  const int i = blockIdx.x * 256 + threadIdx.x;
  if (i >= n4) return;
  const float4 v = ((const float4*)in)[i];
  us4 h, l;
  h.x = f2bf(v.x); l.x = f2bf(v.x - bf2f(h.x));
  h.y = f2bf(v.y); l.y = f2bf(v.y - bf2f(h.y));
  h.z = f2bf(v.z); l.z = f2bf(v.z - bf2f(h.z));
  h.w = f2bf(v.w); l.w = f2bf(v.w - bf2f(h.w));
  ((us4*)hi)[i] = h;
  ((us4*)lo)[i] = l;
}

// ---------------------------------------------------------------------------
// C[M][N] = (Ah+Al)[M][K] @ (Bh+Bl)[N][K]^T + bias[N], fp32-accurate via
// 3-term split-bf16 MFMA: AhBh + AhBl + AlBh (AlBl ~2^-16 rel, dropped).
// 128x128 tile, 256 thr = 4 waves (2x2), wave = 64x64 = 4x4 frags of 16x16.
// mfma_f32_16x16x32_bf16: A/B frag = lane holds row/col (l&15), k = 8*(l>>4)+j
// -> b128 from row-major [row][32k] LDS; +8 ushort pad -> conflict-free
// (row stride 80B = 20 banks; 5r+kg mod 8 covers all residues uniformly).
// C/D: col = l&15, row = 4*(l>>4)+reg  [m89 verified].
// ---------------------------------------------------------------------------
__global__ __launch_bounds__(256) void gemm_split_bt(
    const unsigned short* __restrict__ Ah, const unsigned short* __restrict__ Al,
    const unsigned short* __restrict__ Bh, const unsigned short* __restrict__ Bl,
    const float* __restrict__ bias, float* __restrict__ C,
    int M, int N, int K) {
  constexpr int LDT = 40;   // 32 + 8 pad (16B-aligned rows, conflict-free)
  __shared__ unsigned short sAh[128 * LDT], sAl[128 * LDT];
  __shared__ unsigned short sBh[128 * LDT], sBl[128 * LDT];

  const int tid  = threadIdx.x;
  const int lane = tid & 63;
  const int wv   = tid >> 6;          // wave 0..3
  const int wr   = (wv >> 1) * 64;    // wave row offset in tile
  const int wc   = (wv & 1) * 64;     // wave col offset
  const int bm   = blockIdx.y * 128;
  const int bn   = blockIdx.x * 128;

  // staging: thread -> (row = tid>>1, k-half = (tid&1)*16), 16 bf16 = 2 b128
  const int srow = tid >> 1;
  const int skh  = (tid & 1) * 16;
  const size_t aoff = (size_t)(bm + srow) * K + skh;
  const size_t boff = (size_t)(bn + srow) * K + skh;
  const int swi = srow * LDT + skh;

  // fragment read coords
  const int frow = lane & 15;
  const int fko  = (lane >> 4) * 8;

  f32x4 acc[4][4];
  #pragma unroll
  for (int i = 0; i < 4; ++i)
    #pragma unroll
    for (int j = 0; j < 4; ++j) acc[i][j] = (f32x4){0.f, 0.f, 0.f, 0.f};

  #pragma unroll 1
  for (int k0 = 0; k0 < K; k0 += 32) {
    const short8 gah0 = *(const short8*)(Ah + aoff + k0);
    const short8 gah1 = *(const short8*)(Ah + aoff + k0 + 8);
    const short8 gal0 = *(const short8*)(Al + aoff + k0);
    const short8 gal1 = *(const short8*)(Al + aoff + k0 + 8);
    const short8 gbh0 = *(const short8*)(Bh + boff + k0);
    const short8 gbh1 = *(const short8*)(Bh + boff + k0 + 8);
    const short8 gbl0 = *(const short8*)(Bl + boff + k0);
    const short8 gbl1 = *(const short8*)(Bl + boff + k0 + 8);
    __syncthreads();   // previous iteration's frag reads done
    *(short8*)&sAh[swi]     = gah0;  *(short8*)&sAh[swi + 8] = gah1;
    *(short8*)&sAl[swi]     = gal0;  *(short8*)&sAl[swi + 8] = gal1;
    *(short8*)&sBh[swi]     = gbh0;  *(short8*)&sBh[swi + 8] = gbh1;
    *(short8*)&sBl[swi]     = gbl0;  *(short8*)&sBl[swi + 8] = gbl1;
    __syncthreads();

    short8 fAh[4], fAl[4], fBh[4], fBl[4];
    #pragma unroll
    for (int i = 0; i < 4; ++i) {
      fAh[i] = *(const short8*)&sAh[(wr + 16 * i + frow) * LDT + fko];
      fAl[i] = *(const short8*)&sAl[(wr + 16 * i + frow) * LDT + fko];
      fBh[i] = *(const short8*)&sBh[(wc + 16 * i + frow) * LDT + fko];
      fBl[i] = *(const short8*)&sBl[(wc + 16 * i + frow) * LDT + fko];
    }
    #pragma unroll
    for (int i = 0; i < 4; ++i)
      #pragma unroll
      for (int j = 0; j < 4; ++j) {
        acc[i][j] = __builtin_amdgcn_mfma_f32_16x16x32_bf16(fAh[i], fBh[j], acc[i][j], 0, 0, 0);
        acc[i][j] = __builtin_amdgcn_mfma_f32_16x16x32_bf16(fAh[i], fBl[j], acc[i][j], 0, 0, 0);
        acc[i][j] = __builtin_amdgcn_mfma_f32_16x16x32_bf16(fAl[i], fBh[j], acc[i][j], 0, 0, 0);
      }
  }

  // epilogue: C/D frag -> C[row][col] + bias
  const int r0 = bm + wr + 4 * (lane >> 4);
  const int c0 = bn + wc + frow;
  #pragma unroll
  for (int i = 0; i < 4; ++i)
    #pragma unroll
    for (int j = 0; j < 4; ++j) {
      const int col = c0 + 16 * j;
      const float bv = bias[col];
      #pragma unroll
      for (int rr = 0; rr < 4; ++rr)
        C[(size_t)(r0 + 16 * i + rr) * N + col] = acc[i][j][rr] + bv;
    }
}

// ---------------------------------------------------------------------------
// GQA attention, fp32, flash-style online softmax (unchanged structure; the
// epilogue now emits bf16 hi/lo of O so GEMM2 consumes it directly).
// ---------------------------------------------------------------------------
__global__ __launch_bounds__(256) void attn_kernel(const float* __restrict__ fused,
                                                   unsigned short* __restrict__ oh,
                                                   unsigned short* __restrict__ ol) {
  const int t    = threadIdx.x;
  const int blk  = blockIdx.x;     // 0..511
  const int h    = blk >> 4;       // head 0..31
  const int rb   = blk & 15;       // row block 0..15 (128 rows each)
  const int g    = h >> 2;         // group 0..7
  const int r    = h & 3;          // rep in group
  const int rowl = t >> 1;         // 0..127
  const int half = t & 1;          // which 32 dims of d
  const int srow = rb * 128 + rowl;
  const int d0   = half * 32;
  const int kcol = KOFF + g * 64;
  const int vcol = VOFF + g * 64;

  __shared__ float Ks[KT][64];
  __shared__ float Vs[KT][64];

  float q[32], O[32], s[KT];
  const float* qp = &fused[(size_t)srow * QKVD + g * 256 + r * 64 + d0];
  #pragma unroll
  for (int e4 = 0; e4 < 8; ++e4) {
    const float4 v = *(const float4*)(qp + e4 * 4);
    q[e4*4+0] = v.x * 0.125f; q[e4*4+1] = v.y * 0.125f;
    q[e4*4+2] = v.z * 0.125f; q[e4*4+3] = v.w * 0.125f;
  }
  #pragma unroll
  for (int e = 0; e < 32; ++e) O[e] = 0.f;
  float m = -1e30f, l = 0.f;

  const int lj = t >> 4;          // 0..15
  const int ld = (t & 15) * 4;    // 0..60

  #pragma unroll 1
  for (int kt = 0; kt < SL; kt += KT) {
    __syncthreads();
    *(float4*)&Ks[lj][ld]      = *(const float4*)&fused[(size_t)(kt + lj) * QKVD + kcol + ld];
    *(float4*)&Ks[lj + 16][ld] = *(const float4*)&fused[(size_t)(kt + lj + 16) * QKVD + kcol + ld];
    *(float4*)&Vs[lj][ld]      = *(const float4*)&fused[(size_t)(kt + lj) * QKVD + vcol + ld];
    *(float4*)&Vs[lj + 16][ld] = *(const float4*)&fused[(size_t)(kt + lj + 16) * QKVD + vcol + ld];
    __syncthreads();

    float tmax = -1e30f;
    #pragma unroll
    for (int j = 0; j < KT; ++j) {
      const float4* kr = (const float4*)&Ks[j][d0];
      float p0 = 0.f, p1 = 0.f, p2 = 0.f, p3 = 0.f;
      #pragma unroll
      for (int e8 = 0; e8 < 8; ++e8) {
        const float4 kv = kr[e8];
        p0 += q[e8*4+0] * kv.x;
        p1 += q[e8*4+1] * kv.y;
        p2 += q[e8*4+2] * kv.z;
        p3 += q[e8*4+3] * kv.w;
      }
      const float part = (p0 + p1) + (p2 + p3);
      const float sj = part + __shfl_xor(part, 1, 64);
      s[j] = sj;
      tmax = fmaxf(tmax, sj);
    }

    const float mnew = fmaxf(m, tmax);
    const float corr = __expf(m - mnew);
    l *= corr;
    #pragma unroll
    for (int e = 0; e < 32; ++e) O[e] *= corr;

    #pragma unroll
    for (int j = 0; j < KT; ++j) {
      const float p = __expf(s[j] - mnew);
      l += p;
      const float4* vr = (const float4*)&Vs[j][d0];
      #pragma unroll
      for (int e8 = 0; e8 < 8; ++e8) {
        const float4 vv = vr[e8];
        O[e8*4+0] += p * vv.x;
        O[e8*4+1] += p * vv.y;
        O[e8*4+2] += p * vv.z;
        O[e8*4+3] += p * vv.w;
      }
    }
    m = mnew;
  }

  const float inv = 1.f / l;
  const size_t obase = (size_t)srow * MD + g * 256 + r * 64 + d0;
  unsigned short* ohp = oh + obase;
  unsigned short* olp = ol + obase;
  #pragma unroll
  for (int e4 = 0; e4 < 8; ++e4) {
    us4 vh, vl;
    const float v0 = O[e4*4+0] * inv;
    const float v1 = O[e4*4+1] * inv;
    const float v2 = O[e4*4+2] * inv;
    const float v3 = O[e4*4+3] * inv;
    vh.x = f2bf(v0); vl.x = f2bf(v0 - bf2f(vh.x));
    vh.y = f2bf(v1); vl.y = f2bf(v1 - bf2f(vh.y));
    vh.z = f2bf(v2); vl.z = f2bf(v2 - bf2f(vh.z));
    vh.w = f2bf(v3); vl.w = f2bf(v3 - bf2f(vh.w));
    *(us4*)(ohp + e4 * 4) = vh;
    *(us4*)(olp + e4 * 4) = vl;
  }
}

}  // namespace

extern "C" void kernel_launch(void* const* d_in, const int* in_sizes, int n_in,
                              void* d_out, int out_size, void* d_ws, size_t ws_size,
                              hipStream_t stream) {
  const float* x     = (const float*)d_in[0];
  const float* w_qkv = (const float*)d_in[1];
  const float* b_qkv = (const float*)d_in[2];
  const float* w_out = (const float*)d_in[3];
  const float* b_out = (const float*)d_in[4];
  float* out = (float*)d_out;

  // workspace layout (67.1 MB):
  //   fused fp32 [2048][3072]                 25.2 MB
  //   xh/xl      [2048][2048] bf16 each        8.4 MB x2  (reused as Oh/Ol)
  //   wh/wl      [3072][2048] bf16 each       12.6 MB x2  (reused for w_out)
  float* fused = (float*)d_ws;
  unsigned short* xh = (unsigned short*)(fused + (size_t)SL * QKVD);
  unsigned short* xl = xh + (size_t)SL * MD;
  unsigned short* wh = xl + (size_t)SL * MD;
  unsigned short* wl = wh + (size_t)QKVD * MD;

  const int nx = SL * MD;       // 4.19M
  const int nw = QKVD * MD;     // 6.29M

  split_kernel<<<nx / 1024, 256, 0, stream>>>(x, xh, xl, nx / 4);
  split_kernel<<<nw / 1024, 256, 0, stream>>>(w_qkv, wh, wl, nw / 4);

  // fused = x @ w_qkv^T + b_qkv
  gemm_split_bt<<<dim3(QKVD / 128, SL / 128), 256, 0, stream>>>(
      xh, xl, wh, wl, b_qkv, fused, SL, QKVD, MD);

  // attention -> bf16 hi/lo of O (reuses xh/xl; x-split already consumed)
  attn_kernel<<<dim3(512), 256, 0, stream>>>(fused, xh, xl);

  // split w_out into the (free) w buffers, then out = O @ w_out^T + b_out
  split_kernel<<<nx / 1024, 256, 0, stream>>>(w_out, wh, wl, nx / 4);
  gemm_split_bt<<<dim3(MD / 128, SL / 128), 256, 0, stream>>>(
      xh, xl, wh, wl, b_out, out, SL, MD, MD);
}

// Round 5
// 481.047 us; speedup vs baseline: 3.6416x; 2.8732x over previous
//
#include <hip/hip_runtime.h>
#include <hip/hip_bf16.h>

namespace {

constexpr int MD   = 2048;   // model dim
constexpr int SL   = 2048;   // sequence length
constexpr int QKVD = 3072;   // fused qkv dim

typedef short  short4v __attribute__((ext_vector_type(4)));  // 4 bf16 = 2 VGPRs
typedef short  short8  __attribute__((ext_vector_type(8)));  // 8 bf16 = 4 VGPRs (MFMA operand)
typedef float  f32x4   __attribute__((ext_vector_type(4)));  // MFMA accumulator

typedef unsigned short ushort_t;

// fp32 -> (hi bf16 by truncation, lo bf16 of exact remainder). hi+lo ~ 2^-17 rel.
__device__ __forceinline__ void tsplit(float x, ushort_t& h, ushort_t& l) {
  const unsigned u = __float_as_uint(x);
  h = (ushort_t)(u >> 16);
  const float r = x - __uint_as_float(u & 0xFFFF0000u);   // exact
  l = (ushort_t)(__float_as_uint(r) >> 16);
}

// ---------------------------------------------------------------------------
// fp32 -> bf16 hi/lo split, 4 elems/thread.
// ---------------------------------------------------------------------------
__global__ __launch_bounds__(256) void split_kernel(const float* __restrict__ in,
                                                    ushort_t* __restrict__ hi,
                                                    ushort_t* __restrict__ lo,
                                                    int n4) {
  const int i = blockIdx.x * 256 + threadIdx.x;
  if (i >= n4) return;
  const float4 v = ((const float4*)in)[i];
  ushort_t h0, l0, h1, l1, h2, l2, h3, l3;
  tsplit(v.x, h0, l0); tsplit(v.y, h1, l1);
  tsplit(v.z, h2, l2); tsplit(v.w, h3, l3);
  short4v h = {(short)h0, (short)h1, (short)h2, (short)h3};
  short4v l = {(short)l0, (short)l1, (short)l2, (short)l3};
  ((short4v*)hi)[i] = h;
  ((short4v*)lo)[i] = l;
}

// ---------------------------------------------------------------------------
// C = (Ah+Al) @ (Bh+Bl)^T + bias via 3-term split-bf16 MFMA (fp32-accurate).
// 128x128 tile, 4 waves (2x2), wave = 64x64 = 4x4 frags of 16x16x32.
// SPLIT_OUT=1: emit bf16 hi/lo planes instead of fp32 C.   [proven r1/r2]
// ---------------------------------------------------------------------------
template<bool SPLIT_OUT>
__global__ __launch_bounds__(256) void gemm_split_bt(
    const ushort_t* __restrict__ Ah, const ushort_t* __restrict__ Al,
    const ushort_t* __restrict__ Bh, const ushort_t* __restrict__ Bl,
    const float* __restrict__ bias, float* __restrict__ Cf,
    ushort_t* __restrict__ Ch, ushort_t* __restrict__ Cl,
    int M, int N, int K) {
  constexpr int LDT = 40;   // 32 + 8 pad
  __shared__ ushort_t sAh[128 * LDT], sAl[128 * LDT];
  __shared__ ushort_t sBh[128 * LDT], sBl[128 * LDT];

  const int tid  = threadIdx.x;
  const int lane = tid & 63;
  const int wv   = tid >> 6;
  const int wr   = (wv >> 1) * 64;
  const int wc   = (wv & 1) * 64;
  const int bm   = blockIdx.y * 128;
  const int bn   = blockIdx.x * 128;

  const int srow = tid >> 1;
  const int skh  = (tid & 1) * 16;
  const size_t aoff = (size_t)(bm + srow) * K + skh;
  const size_t boff = (size_t)(bn + srow) * K + skh;
  const int swi = srow * LDT + skh;

  const int frow = lane & 15;
  const int fko  = (lane >> 4) * 8;

  f32x4 acc[4][4];
  #pragma unroll
  for (int i = 0; i < 4; ++i)
    #pragma unroll
    for (int j = 0; j < 4; ++j) acc[i][j] = (f32x4){0.f, 0.f, 0.f, 0.f};

  #pragma unroll 1
  for (int k0 = 0; k0 < K; k0 += 32) {
    const short8 gah0 = *(const short8*)(Ah + aoff + k0);
    const short8 gah1 = *(const short8*)(Ah + aoff + k0 + 8);
    const short8 gal0 = *(const short8*)(Al + aoff + k0);
    const short8 gal1 = *(const short8*)(Al + aoff + k0 + 8);
    const short8 gbh0 = *(const short8*)(Bh + boff + k0);
    const short8 gbh1 = *(const short8*)(Bh + boff + k0 + 8);
    const short8 gbl0 = *(const short8*)(Bl + boff + k0);
    const short8 gbl1 = *(const short8*)(Bl + boff + k0 + 8);
    __syncthreads();
    *(short8*)&sAh[swi]     = gah0;  *(short8*)&sAh[swi + 8] = gah1;
    *(short8*)&sAl[swi]     = gal0;  *(short8*)&sAl[swi + 8] = gal1;
    *(short8*)&sBh[swi]     = gbh0;  *(short8*)&sBh[swi + 8] = gbh1;
    *(short8*)&sBl[swi]     = gbl0;  *(short8*)&sBl[swi + 8] = gbl1;
    __syncthreads();

    short8 fAh[4], fAl[4], fBh[4], fBl[4];
    #pragma unroll
    for (int i = 0; i < 4; ++i) {
      fAh[i] = *(const short8*)&sAh[(wr + 16 * i + frow) * LDT + fko];
      fAl[i] = *(const short8*)&sAl[(wr + 16 * i + frow) * LDT + fko];
      fBh[i] = *(const short8*)&sBh[(wc + 16 * i + frow) * LDT + fko];
      fBl[i] = *(const short8*)&sBl[(wc + 16 * i + frow) * LDT + fko];
    }
    #pragma unroll
    for (int i = 0; i < 4; ++i)
      #pragma unroll
      for (int j = 0; j < 4; ++j) {
        acc[i][j] = __builtin_amdgcn_mfma_f32_16x16x32_bf16(fAh[i], fBh[j], acc[i][j], 0, 0, 0);
        acc[i][j] = __builtin_amdgcn_mfma_f32_16x16x32_bf16(fAh[i], fBl[j], acc[i][j], 0, 0, 0);
        acc[i][j] = __builtin_amdgcn_mfma_f32_16x16x32_bf16(fAl[i], fBh[j], acc[i][j], 0, 0, 0);
      }
  }

  const int r0 = bm + wr + 4 * (lane >> 4);
  const int c0 = bn + wc + frow;
  #pragma unroll
  for (int i = 0; i < 4; ++i)
    #pragma unroll
    for (int j = 0; j < 4; ++j) {
      const int col = c0 + 16 * j;
      const float bv = bias[col];
      #pragma unroll
      for (int rr = 0; rr < 4; ++rr) {
        const size_t idx = (size_t)(r0 + 16 * i + rr) * N + col;
        const float v = acc[i][j][rr] + bv;
        if constexpr (SPLIT_OUT) {
          ushort_t h, l;
          tsplit(v, h, l);
          Ch[idx] = h; Cl[idx] = l;
        } else {
          Cf[idx] = v;
        }
      }
    }
}

// ---------------------------------------------------------------------------
// V transpose: fused cols [2560+g*64, +64) -> Vt[g][d (64)][s (2048)], hi/lo.
// LDS-tiled 64x64; scalar LDS column reads (tiny kernel, ~10us).
// ---------------------------------------------------------------------------
__global__ __launch_bounds__(256) void vtrans_kernel(const ushort_t* __restrict__ Fh,
                                                     const ushort_t* __restrict__ Fl,
                                                     ushort_t* __restrict__ Vth,
                                                     ushort_t* __restrict__ Vtl) {
  __shared__ ushort_t T[64 * 72];   // 72 = 64 + 8 pad (16B-aligned rows)
  const int t    = threadIdx.x;
  const int g    = blockIdx.x >> 5;
  const int s0   = (blockIdx.x & 31) * 64;
  const int srow = t >> 2;            // 0..63
  const int soff = (t & 3) * 16;      // 0,16,32,48 (dual role: d-off / s-off)
  const int vcol = 2560 + g * 64;

  #pragma unroll
  for (int pl = 0; pl < 2; ++pl) {
    const ushort_t* F = pl ? Fl : Fh;
    ushort_t*       D = pl ? Vtl : Vth;
    __syncthreads();
    *(short8*)&T[srow * 72 + soff]     = *(const short8*)&F[(size_t)(s0 + srow) * QKVD + vcol + soff];
    *(short8*)&T[srow * 72 + soff + 8] = *(const short8*)&F[(size_t)(s0 + srow) * QKVD + vcol + soff + 8];
    __syncthreads();
    short8 o0, o1;
    #pragma unroll
    for (int i = 0; i < 8; ++i) o0[i] = (short)T[(soff + i) * 72 + srow];
    #pragma unroll
    for (int i = 0; i < 8; ++i) o1[i] = (short)T[(soff + 8 + i) * 72 + srow];
    *(short8*)&D[(size_t)(g * 64 + srow) * 2048 + s0 + soff]     = o0;
    *(short8*)&D[(size_t)(g * 64 + srow) * 2048 + s0 + soff + 8] = o1;
  }
}

// ---------------------------------------------------------------------------
// GQA flash attention, split-bf16 MFMA (3-term QK^T and PV).
// Block = 4 waves, 64 q-rows, one head. KV tile = 64 keys. No tr-reads:
//   Q  : A-frags in registers from pre-split global bf16.
//   K  : LDS [64 k][64 d] per plane, XOR-swizzled (byte ^= (row&7)<<4).
//   V  : LDS [64 d][64 k] per plane from pre-transposed global Vt, same
//        swizzle -> PV B-frags are plain b128 reads (same pattern as K).
//   P  : per-wave P^T [64 k][16 q] hi/lo in LDS; packed b64 writes, A-frag
//        rebuilt with 8 scalar u16 reads/operand (conflict-free: 4 rows x
//        32B per issue = 2 lanes/bank).
// ---------------------------------------------------------------------------
__global__ __launch_bounds__(256) void attn_mfma(const ushort_t* __restrict__ Fh,
                                                 const ushort_t* __restrict__ Fl,
                                                 const ushort_t* __restrict__ Vth,
                                                 const ushort_t* __restrict__ Vtl,
                                                 ushort_t* __restrict__ Oh,
                                                 ushort_t* __restrict__ Ol) {
  __shared__ ushort_t Kh[64 * 64], Kl[64 * 64];   // [k][d], swizzled, 8KB each
  __shared__ ushort_t Vh[64 * 64], Vl[64 * 64];   // [d][k], swizzled, 8KB each
  __shared__ ushort_t Pt[4 * 2 * 64 * 16];        // [wave][plane][k][q], 16KB

  const int t    = threadIdx.x;
  const int lane = t & 63;
  const int w    = t >> 6;
  const int g16  = lane >> 4;     // 16-lane group 0..3
  const int lq   = lane & 15;

  // XCD-chunked swizzle: XCD x owns heads 4x..4x+3 = group x -> its KV set
  // (K+Vt hi/lo ~1MB) fits the per-XCD L2.
  const int blk0 = blockIdx.x;
  const int blk  = ((blk0 & 7) << 7) | (blk0 >> 3);
  const int head = blk >> 5;      // 0..31
  const int qb   = blk & 31;      // 0..31
  const int g    = head >> 2;
  const int r    = head & 3;
  const int qcol = g * 256 + r * 64;
  const int kcol = 2048 + g * 64;
  const int qrow0 = qb * 64 + w * 16;

  // Q fragments: lane: q = qrow0+lq, d = 32*ts + 8*g16 + j
  short8 qh[2], ql[2];
  {
    const size_t base = (size_t)(qrow0 + lq) * QKVD + qcol + 8 * g16;
    qh[0] = *(const short8*)&Fh[base];      qh[1] = *(const short8*)&Fh[base + 32];
    ql[0] = *(const short8*)&Fl[base];      ql[1] = *(const short8*)&Fl[base + 32];
  }

  f32x4 O[4];
  #pragma unroll
  for (int df = 0; df < 4; ++df) O[df] = (f32x4){0.f, 0.f, 0.f, 0.f};
  float m[4] = {-1e30f, -1e30f, -1e30f, -1e30f};
  float l[4] = {0.f, 0.f, 0.f, 0.f};

  // cooperative staging coords: thread -> (row t>>2, 16-col chunk t&3)
  const int srow = t >> 2;          // 0..63
  const int sdq  = (t & 3) * 16;    // 0,16,32,48
  const unsigned ssw = (unsigned)((srow & 7) << 4);
  const ushort_t* vgh = Vth + (size_t)g * 64 * 2048;
  const ushort_t* vgl = Vtl + (size_t)g * 64 * 2048;

  ushort_t* const ptw = &Pt[w * 2048];   // hi: [0,1024), lo: [1024,2048)

  #pragma unroll 1
  for (int kt = 0; kt < SL; kt += 64) {
    __syncthreads();   // previous tile's LDS reads done
    {
      const size_t rb = (size_t)(kt + srow) * QKVD;
      const short8 ka = *(const short8*)&Fh[rb + kcol + sdq];
      const short8 kb = *(const short8*)&Fh[rb + kcol + sdq + 8];
      const short8 kc = *(const short8*)&Fl[rb + kcol + sdq];
      const short8 kd = *(const short8*)&Fl[rb + kcol + sdq + 8];
      const size_t vb = (size_t)srow * 2048 + kt + sdq;
      const short8 va = *(const short8*)&vgh[vb];
      const short8 vbb = *(const short8*)&vgh[vb + 8];
      const short8 vc = *(const short8*)&vgl[vb];
      const short8 vd = *(const short8*)&vgl[vb + 8];
      const unsigned byt = (unsigned)srow * 128 + (unsigned)sdq * 2;
      *(short8*)((char*)Kh + ((byt)      ^ ssw)) = ka;
      *(short8*)((char*)Kh + ((byt + 16) ^ ssw)) = kb;
      *(short8*)((char*)Kl + ((byt)      ^ ssw)) = kc;
      *(short8*)((char*)Kl + ((byt + 16) ^ ssw)) = kd;
      *(short8*)((char*)Vh + ((byt)      ^ ssw)) = va;
      *(short8*)((char*)Vh + ((byt + 16) ^ ssw)) = vbb;
      *(short8*)((char*)Vl + ((byt)      ^ ssw)) = vc;
      *(short8*)((char*)Vl + ((byt + 16) ^ ssw)) = vd;
    }
    __syncthreads();

    // ---- QK^T: S frag f covers keys 16f..16f+15; 3-term split ----
    f32x4 s4[4];
    #pragma unroll
    for (int f = 0; f < 4; ++f) s4[f] = (f32x4){0.f, 0.f, 0.f, 0.f};
    #pragma unroll
    for (int ts = 0; ts < 2; ++ts) {
      #pragma unroll
      for (int f = 0; f < 4; ++f) {
        const unsigned row = (unsigned)(lq + 16 * f);
        const unsigned byt = (row * 128 + 64 * ts + 16 * g16) ^ ((row & 7) << 4);
        const short8 kbh = *(const short8*)((const char*)Kh + byt);
        const short8 kbl = *(const short8*)((const char*)Kl + byt);
        s4[f] = __builtin_amdgcn_mfma_f32_16x16x32_bf16(qh[ts], kbh, s4[f], 0, 0, 0);
        s4[f] = __builtin_amdgcn_mfma_f32_16x16x32_bf16(qh[ts], kbl, s4[f], 0, 0, 0);
        s4[f] = __builtin_amdgcn_mfma_f32_16x16x32_bf16(ql[ts], kbh, s4[f], 0, 0, 0);
      }
    }

    // ---- online softmax (rows q = 4*g16 + rr; k = lq + 16f) ----
    float tmax[4] = {-1e30f, -1e30f, -1e30f, -1e30f};
    #pragma unroll
    for (int f = 0; f < 4; ++f)
      #pragma unroll
      for (int rr = 0; rr < 4; ++rr) {
        const float sv = s4[f][rr] * 0.125f;
        s4[f][rr] = sv;
        tmax[rr] = fmaxf(tmax[rr], sv);
      }
    #pragma unroll
    for (int off = 1; off < 16; off <<= 1)
      #pragma unroll
      for (int rr = 0; rr < 4; ++rr)
        tmax[rr] = fmaxf(tmax[rr], __shfl_xor(tmax[rr], off, 64));

    float corr[4];
    #pragma unroll
    for (int rr = 0; rr < 4; ++rr) {
      const float mn = fmaxf(m[rr], tmax[rr]);
      corr[rr] = __expf(m[rr] - mn);
      m[rr] = mn;
      l[rr] *= corr[rr];
    }
    float p[4][4];
    #pragma unroll
    for (int f = 0; f < 4; ++f)
      #pragma unroll
      for (int rr = 0; rr < 4; ++rr)
        p[f][rr] = __expf(s4[f][rr] - m[rr]);
    float rs[4];
    #pragma unroll
    for (int rr = 0; rr < 4; ++rr)
      rs[rr] = (p[0][rr] + p[1][rr]) + (p[2][rr] + p[3][rr]);
    #pragma unroll
    for (int off = 1; off < 16; off <<= 1)
      #pragma unroll
      for (int rr = 0; rr < 4; ++rr)
        rs[rr] += __shfl_xor(rs[rr], off, 64);
    #pragma unroll
    for (int rr = 0; rr < 4; ++rr) l[rr] += rs[rr];
    #pragma unroll
    for (int df = 0; df < 4; ++df)
      #pragma unroll
      for (int rr = 0; rr < 4; ++rr) O[df][rr] *= corr[rr];

    // ---- split P, write P^T [k][16q] (hi/lo), packed b64 ----
    #pragma unroll
    for (int f = 0; f < 4; ++f) {
      ushort_t h0, l0, h1, l1, h2, l2, h3, l3;
      tsplit(p[f][0], h0, l0); tsplit(p[f][1], h1, l1);
      tsplit(p[f][2], h2, l2); tsplit(p[f][3], h3, l3);
      const short4v hv = {(short)h0, (short)h1, (short)h2, (short)h3};
      const short4v lv = {(short)l0, (short)l1, (short)l2, (short)l3};
      const int pi = (lq + 16 * f) * 16 + 4 * g16;
      *(short4v*)&ptw[pi]        = hv;
      *(short4v*)&ptw[1024 + pi] = lv;
    }
    asm volatile("s_waitcnt lgkmcnt(0)" ::: "memory");   // wave-local writes landed
    __builtin_amdgcn_sched_barrier(0);

    // ---- PV: A = P^T scalar-rebuilt, B = Vt b128, 3-term split ----
    #pragma unroll
    for (int ts = 0; ts < 2; ++ts) {
      short8 pah, pal;
      #pragma unroll
      for (int j = 0; j < 8; ++j) {
        const int krow = (32 * ts + 8 * g16 + j) * 16 + lq;
        pah[j] = (short)ptw[krow];
        pal[j] = (short)ptw[1024 + krow];
      }
      #pragma unroll
      for (int df = 0; df < 4; ++df) {
        const unsigned vrow = (unsigned)(16 * df + lq);
        const unsigned vbyt = (vrow * 128 + (64 * ts + 16 * g16)) ^ ((vrow & 7) << 4);
        const short8 vbh = *(const short8*)((const char*)Vh + vbyt);
        const short8 vbl = *(const short8*)((const char*)Vl + vbyt);
        O[df] = __builtin_amdgcn_mfma_f32_16x16x32_bf16(pah, vbh, O[df], 0, 0, 0);
        O[df] = __builtin_amdgcn_mfma_f32_16x16x32_bf16(pah, vbl, O[df], 0, 0, 0);
        O[df] = __builtin_amdgcn_mfma_f32_16x16x32_bf16(pal, vbh, O[df], 0, 0, 0);
      }
    }
  }

  // ---- epilogue: normalize, split, store bf16 hi/lo ----
  float inv[4];
  #pragma unroll
  for (int rr = 0; rr < 4; ++rr) inv[rr] = 1.f / l[rr];
  #pragma unroll
  for (int df = 0; df < 4; ++df)
    #pragma unroll
    for (int rr = 0; rr < 4; ++rr) {
      const float v = O[df][rr] * inv[rr];
      ushort_t h, lo16;
      tsplit(v, h, lo16);
      const size_t idx = (size_t)(qrow0 + 4 * g16 + rr) * MD + qcol + 16 * df + lq;
      Oh[idx] = h;
      Ol[idx] = lo16;
    }
}

}  // namespace

extern "C" void kernel_launch(void* const* d_in, const int* in_sizes, int n_in,
                              void* d_out, int out_size, void* d_ws, size_t ws_size,
                              hipStream_t stream) {
  const float* x     = (const float*)d_in[0];
  const float* w_qkv = (const float*)d_in[1];
  const float* b_qkv = (const float*)d_in[2];
  const float* w_out = (const float*)d_in[3];
  const float* b_out = (const float*)d_in[4];
  float* out = (float*)d_out;

  // workspace (67.1 MB of bf16 planes):
  //   xh/xl [2048][2048]  (x split; reused as attn-out Oh/Ol)
  //   wh/wl [3072][2048]  (w_qkv split; Vt aliases wh after gemm1;
  //                        re-split with w_out after attn)
  //   fh/fl [2048][3072]  (fused qkv hi/lo)
  ushort_t* xh = (ushort_t*)d_ws;
  ushort_t* xl = xh + (size_t)SL * MD;
  ushort_t* wh = xl + (size_t)SL * MD;
  ushort_t* wl = wh + (size_t)QKVD * MD;
  ushort_t* fh = wl + (size_t)QKVD * MD;
  ushort_t* fl = fh + (size_t)SL * QKVD;
  ushort_t* vth = wh;                       // 8*64*2048 = 1.05M elems
  ushort_t* vtl = wh + (size_t)8 * 64 * 2048;

  const int nx = SL * MD;       // 4.19M
  const int nw = QKVD * MD;     // 6.29M

  split_kernel<<<nx / 1024, 256, 0, stream>>>(x, xh, xl, nx / 4);
  split_kernel<<<nw / 1024, 256, 0, stream>>>(w_qkv, wh, wl, nw / 4);

  // fused(hi/lo) = x @ w_qkv^T + b_qkv
  gemm_split_bt<true><<<dim3(QKVD / 128, SL / 128), 256, 0, stream>>>(
      xh, xl, wh, wl, b_qkv, nullptr, fh, fl, SL, QKVD, MD);

  // Vt[g][d][s] hi/lo (overwrites wh region — w_qkv split no longer needed)
  vtrans_kernel<<<dim3(256), 256, 0, stream>>>(fh, fl, vth, vtl);

  // attention -> Oh/Ol (reuses xh/xl)
  attn_mfma<<<dim3(1024), 256, 0, stream>>>(fh, fl, vth, vtl, xh, xl);

  // split w_out, then out = O @ w_out^T + b_out (fp32 out)
  split_kernel<<<nx / 1024, 256, 0, stream>>>(w_out, wh, wl, nx / 4);
  gemm_split_bt<false><<<dim3(MD / 128, SL / 128), 256, 0, stream>>>(
      xh, xl, wh, wl, b_out, out, nullptr, nullptr, SL, MD, MD);
}

// Round 7
// 385.060 us; speedup vs baseline: 4.5493x; 1.2493x over previous
//
#include <hip/hip_runtime.h>
#include <hip/hip_bf16.h>

namespace {

constexpr int MD   = 2048;   // model dim
constexpr int SL   = 2048;   // sequence length
constexpr int QKVD = 3072;   // fused qkv dim

typedef short  short4v __attribute__((ext_vector_type(4)));  // 4 bf16
typedef short  short8  __attribute__((ext_vector_type(8)));  // 8 bf16 (MFMA operand)
typedef float  f32x4   __attribute__((ext_vector_type(4)));  // MFMA accumulator

typedef unsigned short ushort_t;

__device__ __forceinline__ ushort_t f2bf_rne(float x) {
  unsigned u = __float_as_uint(x);
  u += 0x7FFFu + ((u >> 16) & 1u);
  return (ushort_t)(u >> 16);
}
__device__ __forceinline__ float bf2f(ushort_t h) {
  return __uint_as_float(((unsigned)h) << 16);
}
// fp32 -> (RNE bf16 hi, bf16 lo of exact residual). RNE hi => dropped-lo terms
// downstream are UNBIASED (matters for 1-term PV / 2-term QK^T).
__device__ __forceinline__ void tsplit(float x, ushort_t& h, ushort_t& l) {
  h = f2bf_rne(x);
  const float r = x - bf2f(h);            // exact in fp32
  l = (ushort_t)(__float_as_uint(r) >> 16);
}

// ---------------------------------------------------------------------------
// fp32 -> bf16 hi/lo split, 4 elems/thread.
// ---------------------------------------------------------------------------
__global__ __launch_bounds__(256) void split_kernel(const float* __restrict__ in,
                                                    ushort_t* __restrict__ hi,
                                                    ushort_t* __restrict__ lo,
                                                    int n4) {
  const int i = blockIdx.x * 256 + threadIdx.x;
  if (i >= n4) return;
  const float4 v = ((const float4*)in)[i];
  ushort_t h0, l0, h1, l1, h2, l2, h3, l3;
  tsplit(v.x, h0, l0); tsplit(v.y, h1, l1);
  tsplit(v.z, h2, l2); tsplit(v.w, h3, l3);
  short4v h = {(short)h0, (short)h1, (short)h2, (short)h3};
  short4v l = {(short)l0, (short)l1, (short)l2, (short)l3};
  ((short4v*)hi)[i] = h;
  ((short4v*)lo)[i] = l;
}

// ---------------------------------------------------------------------------
// C = (Ah+Al) @ (Bh+Bl)^T + bias via 3-term split-bf16 MFMA (fp32-accurate).
// 128x128 tile, 4 waves (2x2), wave = 64x64 = 4x4 frags of 16x16x32.  [proven]
// ---------------------------------------------------------------------------
template<bool SPLIT_OUT>
__global__ __launch_bounds__(256) void gemm_split_bt(
    const ushort_t* __restrict__ Ah, const ushort_t* __restrict__ Al,
    const ushort_t* __restrict__ Bh, const ushort_t* __restrict__ Bl,
    const float* __restrict__ bias, float* __restrict__ Cf,
    ushort_t* __restrict__ Ch, ushort_t* __restrict__ Cl,
    int M, int N, int K) {
  constexpr int LDT = 40;   // 32 + 8 pad
  __shared__ ushort_t sAh[128 * LDT], sAl[128 * LDT];
  __shared__ ushort_t sBh[128 * LDT], sBl[128 * LDT];

  const int tid  = threadIdx.x;
  const int lane = tid & 63;
  const int wv   = tid >> 6;
  const int wr   = (wv >> 1) * 64;
  const int wc   = (wv & 1) * 64;
  const int bm   = blockIdx.y * 128;
  const int bn   = blockIdx.x * 128;

  const int srow = tid >> 1;
  const int skh  = (tid & 1) * 16;
  const size_t aoff = (size_t)(bm + srow) * K + skh;
  const size_t boff = (size_t)(bn + srow) * K + skh;
  const int swi = srow * LDT + skh;

  const int frow = lane & 15;
  const int fko  = (lane >> 4) * 8;

  f32x4 acc[4][4];
  #pragma unroll
  for (int i = 0; i < 4; ++i)
    #pragma unroll
    for (int j = 0; j < 4; ++j) acc[i][j] = (f32x4){0.f, 0.f, 0.f, 0.f};

  #pragma unroll 1
  for (int k0 = 0; k0 < K; k0 += 32) {
    const short8 gah0 = *(const short8*)(Ah + aoff + k0);
    const short8 gah1 = *(const short8*)(Ah + aoff + k0 + 8);
    const short8 gal0 = *(const short8*)(Al + aoff + k0);
    const short8 gal1 = *(const short8*)(Al + aoff + k0 + 8);
    const short8 gbh0 = *(const short8*)(Bh + boff + k0);
    const short8 gbh1 = *(const short8*)(Bh + boff + k0 + 8);
    const short8 gbl0 = *(const short8*)(Bl + boff + k0);
    const short8 gbl1 = *(const short8*)(Bl + boff + k0 + 8);
    __syncthreads();
    *(short8*)&sAh[swi]     = gah0;  *(short8*)&sAh[swi + 8] = gah1;
    *(short8*)&sAl[swi]     = gal0;  *(short8*)&sAl[swi + 8] = gal1;
    *(short8*)&sBh[swi]     = gbh0;  *(short8*)&sBh[swi + 8] = gbh1;
    *(short8*)&sBl[swi]     = gbl0;  *(short8*)&sBl[swi + 8] = gbl1;
    __syncthreads();

    short8 fAh[4], fAl[4], fBh[4], fBl[4];
    #pragma unroll
    for (int i = 0; i < 4; ++i) {
      fAh[i] = *(const short8*)&sAh[(wr + 16 * i + frow) * LDT + fko];
      fAl[i] = *(const short8*)&sAl[(wr + 16 * i + frow) * LDT + fko];
      fBh[i] = *(const short8*)&sBh[(wc + 16 * i + frow) * LDT + fko];
      fBl[i] = *(const short8*)&sBl[(wc + 16 * i + frow) * LDT + fko];
    }
    #pragma unroll
    for (int i = 0; i < 4; ++i)
      #pragma unroll
      for (int j = 0; j < 4; ++j) {
        acc[i][j] = __builtin_amdgcn_mfma_f32_16x16x32_bf16(fAh[i], fBh[j], acc[i][j], 0, 0, 0);
        acc[i][j] = __builtin_amdgcn_mfma_f32_16x16x32_bf16(fAh[i], fBl[j], acc[i][j], 0, 0, 0);
        acc[i][j] = __builtin_amdgcn_mfma_f32_16x16x32_bf16(fAl[i], fBh[j], acc[i][j], 0, 0, 0);
      }
  }

  const int r0 = bm + wr + 4 * (lane >> 4);
  const int c0 = bn + wc + frow;
  #pragma unroll
  for (int i = 0; i < 4; ++i)
    #pragma unroll
    for (int j = 0; j < 4; ++j) {
      const int col = c0 + 16 * j;
      const float bv = bias[col];
      #pragma unroll
      for (int rr = 0; rr < 4; ++rr) {
        const size_t idx = (size_t)(r0 + 16 * i + rr) * N + col;
        const float v = acc[i][j][rr] + bv;
        if constexpr (SPLIT_OUT) {
          ushort_t h, l;
          tsplit(v, h, l);
          Ch[idx] = h; Cl[idx] = l;
        } else {
          Cf[idx] = v;
        }
      }
    }
}

// ---------------------------------------------------------------------------
// V transpose (hi plane only): fused cols [2560+g*64,+64) -> Vt[g][d(64)][s].
// ---------------------------------------------------------------------------
__global__ __launch_bounds__(256) void vtrans_kernel(const ushort_t* __restrict__ Fh,
                                                     ushort_t* __restrict__ Vth) {
  __shared__ ushort_t T[64 * 72];
  const int t    = threadIdx.x;
  const int g    = blockIdx.x >> 5;
  const int s0   = (blockIdx.x & 31) * 64;
  const int srow = t >> 2;
  const int soff = (t & 3) * 16;
  const int vcol = 2560 + g * 64;

  *(short8*)&T[srow * 72 + soff]     = *(const short8*)&Fh[(size_t)(s0 + srow) * QKVD + vcol + soff];
  *(short8*)&T[srow * 72 + soff + 8] = *(const short8*)&Fh[(size_t)(s0 + srow) * QKVD + vcol + soff + 8];
  __syncthreads();
  short8 o0, o1;
  #pragma unroll
  for (int i = 0; i < 8; ++i) o0[i] = (short)T[(soff + i) * 72 + srow];
  #pragma unroll
  for (int i = 0; i < 8; ++i) o1[i] = (short)T[(soff + 8 + i) * 72 + srow];
  *(short8*)&Vth[(size_t)(g * 64 + srow) * 2048 + s0 + soff]     = o0;
  *(short8*)&Vth[(size_t)(g * 64 + srow) * 2048 + s0 + soff + 8] = o1;
}

// ---------------------------------------------------------------------------
// GQA flash attention. Block = 4 waves x 32 q-rows = 128 q, one head.
// KV tile = 64. SWAPPED QK^T: s = mfma(A=K, B=Q) -> per lane P[k][q=lq].
//   Terms: QK^T = kh*(qh+ql) [2-term]; PV = ph*vh [1-term, RNE-unbiased].
//   K,V: LDS [64][64] hi-only... K hi; V hi from pre-transposed Vt[d][s].
//        XOR-swizzled (byte ^= (row&7)<<4) -> conflict-free b128.
//   P: per-wave LDS [32 q][64 k] (swizzled). rr indexes CONSECUTIVE k ->
//      packed b64 writes; read back as b128 A-frags. Wave-local (lgkmcnt).
//   Softmax: in-register over 16 regs + 2 shfl_xor (16,32); corr/l re-
//      distributed to O-rows via 8 bpermutes.
// ---------------------------------------------------------------------------
__global__ __launch_bounds__(256) void attn_mfma(const ushort_t* __restrict__ Fh,
                                                 const ushort_t* __restrict__ Fl,
                                                 const ushort_t* __restrict__ Vth,
                                                 ushort_t* __restrict__ Oh,
                                                 ushort_t* __restrict__ Ol) {
  __shared__ ushort_t Kh[64 * 64];        // [key][d] swizzled, 8KB
  __shared__ ushort_t Vh[64 * 64];        // [d][key] swizzled, 8KB
  __shared__ ushort_t Pq[4 * 32 * 64];    // per-wave [q][k] swizzled, 16KB

  const int t    = threadIdx.x;
  const int lane = t & 63;
  const int w    = t >> 6;
  const int g16  = lane >> 4;
  const int lq   = lane & 15;

  // XCD-chunked swizzle: 512 blocks, XCD x owns heads 4x..4x+3 (= group x).
  const int blk0 = blockIdx.x;
  const int blk  = ((blk0 & 7) << 6) | (blk0 >> 3);
  const int head = blk >> 4;      // 0..31
  const int qb   = blk & 15;      // 0..15 (128 q-rows each)
  const int g    = head >> 2;
  const int r    = head & 3;
  const int qcol = g * 256 + r * 64;
  const int kcol = 2048 + g * 64;
  const int qrow0 = qb * 128 + w * 32;

  // Q B-frags: lane holds Q[q = qrow0+16qa+lq][d = 32ts+8g16+j]
  short8 qh[2][2], ql[2][2];
  #pragma unroll
  for (int qa = 0; qa < 2; ++qa)
    #pragma unroll
    for (int ts = 0; ts < 2; ++ts) {
      const size_t base = (size_t)(qrow0 + 16 * qa + lq) * QKVD + qcol + 32 * ts + 8 * g16;
      qh[qa][ts] = *(const short8*)&Fh[base];
      ql[qa][ts] = *(const short8*)&Fl[base];
    }

  f32x4 O[2][4];
  #pragma unroll
  for (int qa = 0; qa < 2; ++qa)
    #pragma unroll
    for (int df = 0; df < 4; ++df) O[qa][df] = (f32x4){0.f, 0.f, 0.f, 0.f};
  float m[2] = {-1e30f, -1e30f};
  float l[2] = {0.f, 0.f};

  // staging coords
  const int srow = t >> 2;          // 0..63
  const int sdq  = (t & 3) * 16;    // 0,16,32,48
  const unsigned ssw = (unsigned)((srow & 7) << 4);
  const unsigned sb  = (unsigned)srow * 128 + (unsigned)sdq * 2;
  const ushort_t* vg = Vth + (size_t)g * 64 * 2048;
  const unsigned qsw = (unsigned)((lq & 7) << 4);
  char* const pqw = (char*)Pq + w * 4096;

  constexpr float CS = 0.18033688f;   // 0.125 * log2(e)

  #pragma unroll 1
  for (int kt = 0; kt < SL; kt += 64) {
    // issue this tile's global loads early (prior-tile LDS readers still busy)
    const size_t rb = (size_t)(kt + srow) * QKVD + kcol + sdq;
    const short8 ka  = *(const short8*)&Fh[rb];
    const short8 kb  = *(const short8*)&Fh[rb + 8];
    const size_t vb  = (size_t)srow * 2048 + kt + sdq;
    const short8 va  = *(const short8*)&vg[vb];
    const short8 vb8 = *(const short8*)&vg[vb + 8];
    __syncthreads();   // previous tile's LDS reads done
    *(short8*)((char*)Kh + ((sb)      ^ ssw)) = ka;
    *(short8*)((char*)Kh + ((sb + 16) ^ ssw)) = kb;
    *(short8*)((char*)Vh + ((sb)      ^ ssw)) = va;
    *(short8*)((char*)Vh + ((sb + 16) ^ ssw)) = vb8;
    __syncthreads();

    // ---- swapped QK^T: s4[qa][f][rr] = S[key=16f+4g16+rr][q=16qa+lq] ----
    f32x4 s4[2][4];
    #pragma unroll
    for (int qa = 0; qa < 2; ++qa)
      #pragma unroll
      for (int f = 0; f < 4; ++f) s4[qa][f] = (f32x4){0.f, 0.f, 0.f, 0.f};
    #pragma unroll
    for (int ts = 0; ts < 2; ++ts)
      #pragma unroll
      for (int f = 0; f < 4; ++f) {
        const unsigned row = (unsigned)(16 * f + lq);
        const unsigned byt = (row * 128 + 64 * ts + 16 * g16) ^ qsw;
        const short8 kf = *(const short8*)((const char*)Kh + byt);
        #pragma unroll
        for (int qa = 0; qa < 2; ++qa) {
          s4[qa][f] = __builtin_amdgcn_mfma_f32_16x16x32_bf16(kf, qh[qa][ts], s4[qa][f], 0, 0, 0);
          s4[qa][f] = __builtin_amdgcn_mfma_f32_16x16x32_bf16(kf, ql[qa][ts], s4[qa][f], 0, 0, 0);
        }
      }

    // ---- softmax (q = lane-local; keys over 16 regs x 4 lane-groups) ----
    float corr[2];
    #pragma unroll
    for (int qa = 0; qa < 2; ++qa) {
      float tm = s4[qa][0][0];
      #pragma unroll
      for (int f = 0; f < 4; ++f)
        #pragma unroll
        for (int rr = 0; rr < 4; ++rr) tm = fmaxf(tm, s4[qa][f][rr]);
      tm = fmaxf(tm, __shfl_xor(tm, 16, 64));
      tm = fmaxf(tm, __shfl_xor(tm, 32, 64));
      const float mn = fmaxf(m[qa], tm);
      corr[qa] = exp2f((m[qa] - mn) * CS);
      m[qa] = mn;
      float rs = 0.f;
      #pragma unroll
      for (int f = 0; f < 4; ++f)
        #pragma unroll
        for (int rr = 0; rr < 4; ++rr) {
          const float p = exp2f((s4[qa][f][rr] - mn) * CS);
          s4[qa][f][rr] = p;
          rs += p;
        }
      rs += __shfl_xor(rs, 16, 64);
      rs += __shfl_xor(rs, 32, 64);
      l[qa] = l[qa] * corr[qa] + rs;
    }
    // O-rescale: O rows are q=16qa+4g16+rr; fetch that q's corr via bpermute
    #pragma unroll
    for (int qa = 0; qa < 2; ++qa)
      #pragma unroll
      for (int rr = 0; rr < 4; ++rr) {
        const float c = __shfl(corr[qa], 20 * g16 + rr, 64);
        #pragma unroll
        for (int df = 0; df < 4; ++df) O[qa][df][rr] *= c;
      }

    // ---- P write: rr = consecutive k -> packed b64 into P[q][k] ----
    #pragma unroll
    for (int qa = 0; qa < 2; ++qa)
      #pragma unroll
      for (int f = 0; f < 4; ++f) {
        short4v pv = {(short)f2bf_rne(s4[qa][f][0]), (short)f2bf_rne(s4[qa][f][1]),
                      (short)f2bf_rne(s4[qa][f][2]), (short)f2bf_rne(s4[qa][f][3])};
        const unsigned pb = ((unsigned)(16 * qa + lq) * 128 + (unsigned)(32 * f + 8 * g16)) ^ qsw;
        *(short4v*)(pqw + pb) = pv;
      }
    asm volatile("s_waitcnt lgkmcnt(0)" ::: "memory");   // wave-local P landed
    __builtin_amdgcn_sched_barrier(0);

    // ---- PV (1-term): A = P[q][k] b128, B = V[d][k] b128 ----
    #pragma unroll
    for (int qa = 0; qa < 2; ++qa)
      #pragma unroll
      for (int ts = 0; ts < 2; ++ts) {
        const unsigned pa = ((unsigned)(16 * qa + lq) * 128 + (unsigned)(16 * g16 + 64 * ts)) ^ qsw;
        const short8 pfrag = *(const short8*)(pqw + pa);
        #pragma unroll
        for (int df = 0; df < 4; ++df) {
          const unsigned vrow = (unsigned)(16 * df + lq);
          const unsigned vbyt = (vrow * 128 + 16 * g16 + 64 * ts) ^ qsw;
          const short8 vf = *(const short8*)((const char*)Vh + vbyt);
          O[qa][df] = __builtin_amdgcn_mfma_f32_16x16x32_bf16(pfrag, vf, O[qa][df], 0, 0, 0);
        }
      }
  }

  // ---- epilogue: normalize (per-row l via bpermute), split-store ----
  #pragma unroll
  for (int qa = 0; qa < 2; ++qa) {
    const float inv = 1.f / l[qa];
    #pragma unroll
    for (int rr = 0; rr < 4; ++rr) {
      const float ir = __shfl(inv, 20 * g16 + rr, 64);
      #pragma unroll
      for (int df = 0; df < 4; ++df) {
        const float v = O[qa][df][rr] * ir;
        ushort_t h, lo16;
        tsplit(v, h, lo16);
        const size_t idx = (size_t)(qrow0 + 16 * qa + 4 * g16 + rr) * MD + qcol + 16 * df + lq;
        Oh[idx] = h;
        Ol[idx] = lo16;
      }
    }
  }
}

}  // namespace

extern "C" void kernel_launch(void* const* d_in, const int* in_sizes, int n_in,
                              void* d_out, int out_size, void* d_ws, size_t ws_size,
                              hipStream_t stream) {
  const float* x     = (const float*)d_in[0];
  const float* w_qkv = (const float*)d_in[1];
  const float* b_qkv = (const float*)d_in[2];
  const float* w_out = (const float*)d_in[3];
  const float* b_out = (const float*)d_in[4];
  float* out = (float*)d_out;

  ushort_t* xh = (ushort_t*)d_ws;
  ushort_t* xl = xh + (size_t)SL * MD;
  ushort_t* wh = xl + (size_t)SL * MD;
  ushort_t* wl = wh + (size_t)QKVD * MD;
  ushort_t* fh = wl + (size_t)QKVD * MD;
  ushort_t* fl = fh + (size_t)SL * QKVD;
  ushort_t* vth = wh;                       // aliases retired w_qkv-hi region

  const int nx = SL * MD;
  const int nw = QKVD * MD;

  split_kernel<<<nx / 1024, 256, 0, stream>>>(x, xh, xl, nx / 4);
  split_kernel<<<nw / 1024, 256, 0, stream>>>(w_qkv, wh, wl, nw / 4);

  gemm_split_bt<true><<<dim3(QKVD / 128, SL / 128), 256, 0, stream>>>(
      xh, xl, wh, wl, b_qkv, nullptr, fh, fl, SL, QKVD, MD);

  vtrans_kernel<<<dim3(256), 256, 0, stream>>>(fh, vth);

  attn_mfma<<<dim3(512), 256, 0, stream>>>(fh, fl, vth, xh, xl);

  split_kernel<<<nx / 1024, 256, 0, stream>>>(w_out, wh, wl, nx / 4);
  gemm_split_bt<false><<<dim3(MD / 128, SL / 128), 256, 0, stream>>>(
      xh, xl, wh, wl, b_out, out, nullptr, nullptr, SL, MD, MD);
}

// Round 9
// 375.731 us; speedup vs baseline: 4.6623x; 1.0248x over previous
//
#include <hip/hip_runtime.h>
#include <hip/hip_bf16.h>

namespace {

constexpr int MD   = 2048;   // model dim
constexpr int SL   = 2048;   // sequence length
constexpr int QKVD = 3072;   // fused qkv dim

typedef short  short4v __attribute__((ext_vector_type(4)));  // 4 bf16
typedef short  short8  __attribute__((ext_vector_type(8)));  // 8 bf16 (MFMA operand)
typedef float  f32x4   __attribute__((ext_vector_type(4)));  // MFMA accumulator

typedef unsigned short ushort_t;

__device__ __forceinline__ ushort_t f2bf_rne(float x) {
  unsigned u = __float_as_uint(x);
  u += 0x7FFFu + ((u >> 16) & 1u);
  return (ushort_t)(u >> 16);
}
__device__ __forceinline__ float bf2f(ushort_t h) {
  return __uint_as_float(((unsigned)h) << 16);
}
// fp32 -> (RNE bf16 hi, bf16 lo of exact residual).
__device__ __forceinline__ void tsplit(float x, ushort_t& h, ushort_t& l) {
  h = f2bf_rne(x);
  const float r = x - bf2f(h);            // exact in fp32
  l = (ushort_t)(__float_as_uint(r) >> 16);
}

// async global->LDS DMA, 16B per lane (dest = wave-uniform base + lane*16)
__device__ __forceinline__ void gl16(const void* g, void* l) {
  __builtin_amdgcn_global_load_lds(
      (const __attribute__((address_space(1))) unsigned int*)g,
      (__attribute__((address_space(3))) unsigned int*)l, 16, 0, 0);
}

// ---------------------------------------------------------------------------
// fp32 -> bf16 hi/lo split, 4 elems/thread.
// ---------------------------------------------------------------------------
__global__ __launch_bounds__(256) void split_kernel(const float* __restrict__ in,
                                                    ushort_t* __restrict__ hi,
                                                    ushort_t* __restrict__ lo,
                                                    int n4) {
  const int i = blockIdx.x * 256 + threadIdx.x;
  if (i >= n4) return;
  const float4 v = ((const float4*)in)[i];
  ushort_t h0, l0, h1, l1, h2, l2, h3, l3;
  tsplit(v.x, h0, l0); tsplit(v.y, h1, l1);
  tsplit(v.z, h2, l2); tsplit(v.w, h3, l3);
  short4v h = {(short)h0, (short)h1, (short)h2, (short)h3};
  short4v l = {(short)l0, (short)l1, (short)l2, (short)l3};
  ((short4v*)hi)[i] = h;
  ((short4v*)lo)[i] = l;
}

// ---------------------------------------------------------------------------
// C = (Ah+Al) @ (Bh+Bl)^T + bias via 3-term split-bf16 MFMA (fp32-accurate).
// 128x128 tile, BK=32, 4 waves (2x2), wave = 64x64 = 4x4 frags of 16x16x32.
// Staging via global_load_lds width-16 (no reg round-trip): LDS per plane =
// linear [128 rows][4 chunks x 16B]; chunk swizzle c ^= (row>>1)&3 applied
// to SOURCE addr and frag READ (dest linear per m104/m173).
// ---------------------------------------------------------------------------
template<bool SPLIT_OUT>
__global__ __launch_bounds__(256) void gemm_split_bt(
    const ushort_t* __restrict__ Ah, const ushort_t* __restrict__ Al,
    const ushort_t* __restrict__ Bh, const ushort_t* __restrict__ Bl,
    const float* __restrict__ bias, float* __restrict__ Cf,
    ushort_t* __restrict__ Ch, ushort_t* __restrict__ Cl,
    int M, int N, int K) {
  __shared__ ushort_t sAh[128 * 32], sAl[128 * 32];   // 8KB each, 32KB total
  __shared__ ushort_t sBh[128 * 32], sBl[128 * 32];

  const int tid  = threadIdx.x;
  const int lane = tid & 63;
  const int wv   = tid >> 6;
  const int wr   = (wv >> 1) * 64;
  const int wc   = (wv & 1) * 64;
  const int bm   = blockIdx.y * 128;
  const int bn   = blockIdx.x * 128;

  // staging geometry: wave wv issues calls c0=2wv, c0+1 per plane; call c
  // covers rows 16c..16c+15 (lane>>2), chunk = lane&3. Source chunk is
  // pre-swizzled: sq = chunk ^ ((row>>1)&3)  (same for row and row+16).
  const int c0   = 2 * wv;
  const int sr0  = c0 * 16 + (lane >> 2);
  const int sr1  = sr0 + 16;
  const int sq   = (lane & 3) ^ ((sr0 >> 1) & 3);
  const ushort_t* pAh0 = Ah + (size_t)(bm + sr0) * K + 8 * sq;
  const ushort_t* pAh1 = Ah + (size_t)(bm + sr1) * K + 8 * sq;
  const ushort_t* pAl0 = Al + (size_t)(bm + sr0) * K + 8 * sq;
  const ushort_t* pAl1 = Al + (size_t)(bm + sr1) * K + 8 * sq;
  const ushort_t* pBh0 = Bh + (size_t)(bn + sr0) * K + 8 * sq;
  const ushort_t* pBh1 = Bh + (size_t)(bn + sr1) * K + 8 * sq;
  const ushort_t* pBl0 = Bl + (size_t)(bn + sr0) * K + 8 * sq;
  const ushort_t* pBl1 = Bl + (size_t)(bn + sr1) * K + 8 * sq;
  ushort_t* const dAh0 = &sAh[c0 * 512];  ushort_t* const dAh1 = &sAh[c0 * 512 + 512];
  ushort_t* const dAl0 = &sAl[c0 * 512];  ushort_t* const dAl1 = &sAl[c0 * 512 + 512];
  ushort_t* const dBh0 = &sBh[c0 * 512];  ushort_t* const dBh1 = &sBh[c0 * 512 + 512];
  ushort_t* const dBl0 = &sBl[c0 * 512];  ushort_t* const dBl1 = &sBl[c0 * 512 + 512];

  // fragment read offsets (loop-invariant; +1024*i covers rows +16i since
  // the swizzle bits (row>>1)&3 are unchanged by +16)
  const int frow = lane & 15;
  const int fq   = lane >> 4;
  const unsigned oA = (unsigned)(wr + frow) * 64 + ((unsigned)(fq ^ ((frow >> 1) & 3)) << 4);
  const unsigned oB = (unsigned)(wc + frow) * 64 + ((unsigned)(fq ^ ((frow >> 1) & 3)) << 4);

  f32x4 acc[4][4];
  #pragma unroll
  for (int i = 0; i < 4; ++i)
    #pragma unroll
    for (int j = 0; j < 4; ++j) acc[i][j] = (f32x4){0.f, 0.f, 0.f, 0.f};

  #pragma unroll 1
  for (int k0 = 0; k0 < K; k0 += 32) {
    __syncthreads();   // all waves done reading previous tile
    gl16(pAh0, dAh0);  gl16(pAh1, dAh1);
    gl16(pAl0, dAl0);  gl16(pAl1, dAl1);
    gl16(pBh0, dBh0);  gl16(pBh1, dBh1);
    gl16(pBl0, dBl0);  gl16(pBl1, dBl1);
    pAh0 += 32; pAh1 += 32; pAl0 += 32; pAl1 += 32;
    pBh0 += 32; pBh1 += 32; pBl0 += 32; pBl1 += 32;
    __syncthreads();   // compiler drains vmcnt(0) before barrier -> LDS ready

    short8 fAh[4], fAl[4], fBh[4], fBl[4];
    #pragma unroll
    for (int i = 0; i < 4; ++i) {
      fAh[i] = *(const short8*)((const char*)sAh + oA + 1024u * i);
      fAl[i] = *(const short8*)((const char*)sAl + oA + 1024u * i);
      fBh[i] = *(const short8*)((const char*)sBh + oB + 1024u * i);
      fBl[i] = *(const short8*)((const char*)sBl + oB + 1024u * i);
    }
    #pragma unroll
    for (int i = 0; i < 4; ++i)
      #pragma unroll
      for (int j = 0; j < 4; ++j) {
        acc[i][j] = __builtin_amdgcn_mfma_f32_16x16x32_bf16(fAh[i], fBh[j], acc[i][j], 0, 0, 0);
        acc[i][j] = __builtin_amdgcn_mfma_f32_16x16x32_bf16(fAh[i], fBl[j], acc[i][j], 0, 0, 0);
        acc[i][j] = __builtin_amdgcn_mfma_f32_16x16x32_bf16(fAl[i], fBh[j], acc[i][j], 0, 0, 0);
      }
  }

  const int r0 = bm + wr + 4 * (lane >> 4);
  const int c0e = bn + wc + frow;
  #pragma unroll
  for (int i = 0; i < 4; ++i)
    #pragma unroll
    for (int j = 0; j < 4; ++j) {
      const int col = c0e + 16 * j;
      const float bv = bias[col];
      #pragma unroll
      for (int rr = 0; rr < 4; ++rr) {
        const size_t idx = (size_t)(r0 + 16 * i + rr) * N + col;
        const float v = acc[i][j][rr] + bv;
        if constexpr (SPLIT_OUT) {
          ushort_t h, l;
          tsplit(v, h, l);
          Ch[idx] = h; Cl[idx] = l;
        } else {
          Cf[idx] = v;
        }
      }
    }
}

// ---------------------------------------------------------------------------
// V transpose (hi plane only): fused cols [2560+g*64,+64) -> Vt[g][d(64)][s].
// ---------------------------------------------------------------------------
__global__ __launch_bounds__(256) void vtrans_kernel(const ushort_t* __restrict__ Fh,
                                                     ushort_t* __restrict__ Vth) {
  __shared__ ushort_t T[64 * 72];
  const int t    = threadIdx.x;
  const int g    = blockIdx.x >> 5;
  const int s0   = (blockIdx.x & 31) * 64;
  const int srow = t >> 2;
  const int soff = (t & 3) * 16;
  const int vcol = 2560 + g * 64;

  *(short8*)&T[srow * 72 + soff]     = *(const short8*)&Fh[(size_t)(s0 + srow) * QKVD + vcol + soff];
  *(short8*)&T[srow * 72 + soff + 8] = *(const short8*)&Fh[(size_t)(s0 + srow) * QKVD + vcol + soff + 8];
  __syncthreads();
  short8 o0, o1;
  #pragma unroll
  for (int i = 0; i < 8; ++i) o0[i] = (short)T[(soff + i) * 72 + srow];
  #pragma unroll
  for (int i = 0; i < 8; ++i) o1[i] = (short)T[(soff + 8 + i) * 72 + srow];
  *(short8*)&Vth[(size_t)(g * 64 + srow) * 2048 + s0 + soff]     = o0;
  *(short8*)&Vth[(size_t)(g * 64 + srow) * 2048 + s0 + soff + 8] = o1;
}

// ---------------------------------------------------------------------------
// GQA flash attention. Block = 4 waves x 32 q-rows = 128 q, one head.
// KV tile = 64. SWAPPED QK^T (A=K, B=Q). 2-term QK^T, 1-term RNE PV.
// T13 defer-rescale: skip corr/O-rescale when no q-row's tile-max exceeds
// running max by >8 raw-score units (P then bounded by e^1).
// ---------------------------------------------------------------------------
__global__ __launch_bounds__(256) void attn_mfma(const ushort_t* __restrict__ Fh,
                                                 const ushort_t* __restrict__ Fl,
                                                 const ushort_t* __restrict__ Vth,
                                                 ushort_t* __restrict__ Oh,
                                                 ushort_t* __restrict__ Ol) {
  __shared__ ushort_t Kh[64 * 64];        // [key][d] swizzled, 8KB
  __shared__ ushort_t Vh[64 * 64];        // [d][key] swizzled, 8KB
  __shared__ ushort_t Pq[4 * 32 * 64];    // per-wave [q][k] swizzled, 16KB

  const int t    = threadIdx.x;
  const int lane = t & 63;
  const int w    = t >> 6;
  const int g16  = lane >> 4;
  const int lq   = lane & 15;

  // XCD-chunked swizzle: 512 blocks, XCD x owns heads 4x..4x+3 (= group x).
  const int blk0 = blockIdx.x;
  const int blk  = ((blk0 & 7) << 6) | (blk0 >> 3);
  const int head = blk >> 4;      // 0..31
  const int qb   = blk & 15;      // 0..15 (128 q-rows each)
  const int g    = head >> 2;
  const int r    = head & 3;
  const int qcol = g * 256 + r * 64;
  const int kcol = 2048 + g * 64;
  const int qrow0 = qb * 128 + w * 32;

  // Q B-frags: lane holds Q[q = qrow0+16qa+lq][d = 32ts+8g16+j]
  short8 qh[2][2], ql[2][2];
  #pragma unroll
  for (int qa = 0; qa < 2; ++qa)
    #pragma unroll
    for (int ts = 0; ts < 2; ++ts) {
      const size_t base = (size_t)(qrow0 + 16 * qa + lq) * QKVD + qcol + 32 * ts + 8 * g16;
      qh[qa][ts] = *(const short8*)&Fh[base];
      ql[qa][ts] = *(const short8*)&Fl[base];
    }

  f32x4 O[2][4];
  #pragma unroll
  for (int qa = 0; qa < 2; ++qa)
    #pragma unroll
    for (int df = 0; df < 4; ++df) O[qa][df] = (f32x4){0.f, 0.f, 0.f, 0.f};
  float m[2] = {-1e30f, -1e30f};
  float l[2] = {0.f, 0.f};

  // staging coords
  const int srow = t >> 2;          // 0..63
  const int sdq  = (t & 3) * 16;    // 0,16,32,48
  const unsigned ssw = (unsigned)((srow & 7) << 4);
  const unsigned sb  = (unsigned)srow * 128 + (unsigned)sdq * 2;
  const ushort_t* vg = Vth + (size_t)g * 64 * 2048;
  const unsigned qsw = (unsigned)((lq & 7) << 4);
  char* const pqw = (char*)Pq + w * 4096;

  constexpr float CS = 0.18033688f;   // 0.125 * log2(e)

  #pragma unroll 1
  for (int kt = 0; kt < SL; kt += 64) {
    // issue this tile's global loads early (prior-tile LDS readers still busy)
    const size_t rb = (size_t)(kt + srow) * QKVD + kcol + sdq;
    const short8 ka  = *(const short8*)&Fh[rb];
    const short8 kb  = *(const short8*)&Fh[rb + 8];
    const size_t vb  = (size_t)srow * 2048 + kt + sdq;
    const short8 va  = *(const short8*)&vg[vb];
    const short8 vb8 = *(const short8*)&vg[vb + 8];
    __syncthreads();   // previous tile's LDS reads done
    *(short8*)((char*)Kh + ((sb)      ^ ssw)) = ka;
    *(short8*)((char*)Kh + ((sb + 16) ^ ssw)) = kb;
    *(short8*)((char*)Vh + ((sb)      ^ ssw)) = va;
    *(short8*)((char*)Vh + ((sb + 16) ^ ssw)) = vb8;
    __syncthreads();

    // ---- swapped QK^T: s4[qa][f][rr] = S[key=16f+4g16+rr][q=16qa+lq] ----
    f32x4 s4[2][4];
    #pragma unroll
    for (int qa = 0; qa < 2; ++qa)
      #pragma unroll
      for (int f = 0; f < 4; ++f) s4[qa][f] = (f32x4){0.f, 0.f, 0.f, 0.f};
    #pragma unroll
    for (int ts = 0; ts < 2; ++ts)
      #pragma unroll
      for (int f = 0; f < 4; ++f) {
        const unsigned row = (unsigned)(16 * f + lq);
        const unsigned byt = (row * 128 + 64 * ts + 16 * g16) ^ qsw;
        const short8 kf = *(const short8*)((const char*)Kh + byt);
        #pragma unroll
        for (int qa = 0; qa < 2; ++qa) {
          s4[qa][f] = __builtin_amdgcn_mfma_f32_16x16x32_bf16(kf, qh[qa][ts], s4[qa][f], 0, 0, 0);
          s4[qa][f] = __builtin_amdgcn_mfma_f32_16x16x32_bf16(kf, ql[qa][ts], s4[qa][f], 0, 0, 0);
        }
      }

    // ---- softmax with T13 defer-rescale ----
    float tm[2];
    #pragma unroll
    for (int qa = 0; qa < 2; ++qa) {
      float tmx = s4[qa][0][0];
      #pragma unroll
      for (int f = 0; f < 4; ++f)
        #pragma unroll
        for (int rr = 0; rr < 4; ++rr) tmx = fmaxf(tmx, s4[qa][f][rr]);
      tmx = fmaxf(tmx, __shfl_xor(tmx, 16, 64));
      tmx = fmaxf(tmx, __shfl_xor(tmx, 32, 64));
      tm[qa] = tmx;
    }
    const bool grow = (tm[0] > m[0] + 8.f) || (tm[1] > m[1] + 8.f);
    if (__any((int)grow)) {
      float corr[2];
      #pragma unroll
      for (int qa = 0; qa < 2; ++qa) {
        const float mn = fmaxf(m[qa], tm[qa]);
        corr[qa] = exp2f((m[qa] - mn) * CS);
        m[qa] = mn;
        l[qa] *= corr[qa];
      }
      #pragma unroll
      for (int qa = 0; qa < 2; ++qa)
        #pragma unroll
        for (int rr = 0; rr < 4; ++rr) {
          const float c = __shfl(corr[qa], 20 * g16 + rr, 64);
          #pragma unroll
          for (int df = 0; df < 4; ++df) O[qa][df][rr] *= c;
        }
    }
    #pragma unroll
    for (int qa = 0; qa < 2; ++qa) {
      float rs = 0.f;
      #pragma unroll
      for (int f = 0; f < 4; ++f)
        #pragma unroll
        for (int rr = 0; rr < 4; ++rr) {
          const float p = exp2f((s4[qa][f][rr] - m[qa]) * CS);
          s4[qa][f][rr] = p;
          rs += p;
        }
      rs += __shfl_xor(rs, 16, 64);
      rs += __shfl_xor(rs, 32, 64);
      l[qa] += rs;
    }

    // ---- P write: rr = consecutive k -> packed b64 into P[q][k] ----
    #pragma unroll
    for (int qa = 0; qa < 2; ++qa)
      #pragma unroll
      for (int f = 0; f < 4; ++f) {
        short4v pv = {(short)f2bf_rne(s4[qa][f][0]), (short)f2bf_rne(s4[qa][f][1]),
                      (short)f2bf_rne(s4[qa][f][2]), (short)f2bf_rne(s4[qa][f][3])};
        const unsigned pb = ((unsigned)(16 * qa + lq) * 128 + (unsigned)(32 * f + 8 * g16)) ^ qsw;
        *(short4v*)(pqw + pb) = pv;
      }
    asm volatile("s_waitcnt lgkmcnt(0)" ::: "memory");   // wave-local P landed
    __builtin_amdgcn_sched_barrier(0);

    // ---- PV (1-term): A = P[q][k] b128, B = V[d][k] b128 ----
    #pragma unroll
    for (int qa = 0; qa < 2; ++qa)
      #pragma unroll
      for (int ts = 0; ts < 2; ++ts) {
        const unsigned pa = ((unsigned)(16 * qa + lq) * 128 + (unsigned)(16 * g16 + 64 * ts)) ^ qsw;
        const short8 pfrag = *(const short8*)(pqw + pa);
        #pragma unroll
        for (int df = 0; df < 4; ++df) {
          const unsigned vrow = (unsigned)(16 * df + lq);
          const unsigned vbyt = (vrow * 128 + 16 * g16 + 64 * ts) ^ qsw;
          const short8 vf = *(const short8*)((const char*)Vh + vbyt);
          O[qa][df] = __builtin_amdgcn_mfma_f32_16x16x32_bf16(pfrag, vf, O[qa][df], 0, 0, 0);
        }
      }
  }

  // ---- epilogue: normalize (per-row l via bpermute), split-store ----
  #pragma unroll
  for (int qa = 0; qa < 2; ++qa) {
    const float inv = 1.f / l[qa];
    #pragma unroll
    for (int rr = 0; rr < 4; ++rr) {
      const float ir = __shfl(inv, 20 * g16 + rr, 64);
      #pragma unroll
      for (int df = 0; df < 4; ++df) {
        const float v = O[qa][df][rr] * ir;
        ushort_t h, lo16;
        tsplit(v, h, lo16);
        const size_t idx = (size_t)(qrow0 + 16 * qa + 4 * g16 + rr) * MD + qcol + 16 * df + lq;
        Oh[idx] = h;
        Ol[idx] = lo16;
      }
    }
  }
}

}  // namespace

extern "C" void kernel_launch(void* const* d_in, const int* in_sizes, int n_in,
                              void* d_out, int out_size, void* d_ws, size_t ws_size,
                              hipStream_t stream) {
  const float* x     = (const float*)d_in[0];
  const float* w_qkv = (const float*)d_in[1];
  const float* b_qkv = (const float*)d_in[2];
  const float* w_out = (const float*)d_in[3];
  const float* b_out = (const float*)d_in[4];
  float* out = (float*)d_out;

  ushort_t* xh = (ushort_t*)d_ws;
  ushort_t* xl = xh + (size_t)SL * MD;
  ushort_t* wh = xl + (size_t)SL * MD;
  ushort_t* wl = wh + (size_t)QKVD * MD;
  ushort_t* fh = wl + (size_t)QKVD * MD;
  ushort_t* fl = fh + (size_t)SL * QKVD;
  ushort_t* vth = wh;                       // aliases retired w_qkv-hi region

  const int nx = SL * MD;
  const int nw = QKVD * MD;

  split_kernel<<<nx / 1024, 256, 0, stream>>>(x, xh, xl, nx / 4);
  split_kernel<<<nw / 1024, 256, 0, stream>>>(w_qkv, wh, wl, nw / 4);

  gemm_split_bt<true><<<dim3(QKVD / 128, SL / 128), 256, 0, stream>>>(
      xh, xl, wh, wl, b_qkv, nullptr, fh, fl, SL, QKVD, MD);

  vtrans_kernel<<<dim3(256), 256, 0, stream>>>(fh, vth);

  attn_mfma<<<dim3(512), 256, 0, stream>>>(fh, fl, vth, xh, xl);

  split_kernel<<<nx / 1024, 256, 0, stream>>>(w_out, wh, wl, nx / 4);
  gemm_split_bt<false><<<dim3(MD / 128, SL / 128), 256, 0, stream>>>(
      xh, xl, wh, wl, b_out, out, nullptr, nullptr, SL, MD, MD);
}